// Round 1
// baseline (452.687 us; speedup 1.0000x reference)
//
#include <hip/hip_runtime.h>
#include <hip/hip_bf16.h>
#include <cstdint>
#include <cstddef>

#define Bn 64
#define Mn 512
#define Dn 2048
#define Kn 32
#define EPSF 1e-12f

typedef __attribute__((ext_vector_type(8))) __bf16 bf16x8;
typedef __attribute__((ext_vector_type(4))) __bf16 bf16x4;
typedef __attribute__((ext_vector_type(4))) float f32x4;

// ---------------- K0: convert W to bf16, zero ssq accumulators ----------------
__global__ __launch_bounds__(256) void k0_prep(const float* __restrict__ W,
                                               __bf16* __restrict__ Wb,
                                               float* __restrict__ ssq) {
  int idx = blockIdx.x * 256 + threadIdx.x;
  if (idx < Kn * Dn) Wb[idx] = (__bf16)W[idx];
  if (idx < Bn * Kn) ssq[idx] = 0.f;
}

// ---------------- K1: raw logits = x . W^T (bf16 MFMA) + row sumsq -> invnorm --
// One wave per 16 rows. A-frag: lane holds x[row0+(l&15)][32s + 8q + j] (fp32
// loaded, converted in-register). B-frag: W[l&15 (+16)][32s + 8q + j] bf16
// direct (B^T-style row-major = ideal MFMA layout). No LDS.
__global__ __launch_bounds__(256) void k1_logits(const float* __restrict__ x,
                                                 const __bf16* __restrict__ Wb,
                                                 float* __restrict__ logits,
                                                 float* __restrict__ invn) {
  int wv = threadIdx.x >> 6, lane = threadIdx.x & 63;
  int mr = lane & 15, q = lane >> 4;
  int row0 = (blockIdx.x * 4 + wv) * 16;
  const float* xp = x + (size_t)(row0 + mr) * Dn + q * 8;
  const __bf16* wp = Wb + (size_t)mr * Dn + q * 8;
  f32x4 acc0 = {0.f, 0.f, 0.f, 0.f};
  f32x4 acc1 = {0.f, 0.f, 0.f, 0.f};
  float ssq = 0.f;
#pragma unroll 2
  for (int s = 0; s < 64; ++s) {
    f32x4 xa = *(const f32x4*)(xp + s * 32);
    f32x4 xb = *(const f32x4*)(xp + s * 32 + 4);
    bf16x8 af;
    af[0] = (__bf16)xa[0]; af[1] = (__bf16)xa[1];
    af[2] = (__bf16)xa[2]; af[3] = (__bf16)xa[3];
    af[4] = (__bf16)xb[0]; af[5] = (__bf16)xb[1];
    af[6] = (__bf16)xb[2]; af[7] = (__bf16)xb[3];
    ssq = fmaf(xa[0], xa[0], ssq); ssq = fmaf(xa[1], xa[1], ssq);
    ssq = fmaf(xa[2], xa[2], ssq); ssq = fmaf(xa[3], xa[3], ssq);
    ssq = fmaf(xb[0], xb[0], ssq); ssq = fmaf(xb[1], xb[1], ssq);
    ssq = fmaf(xb[2], xb[2], ssq); ssq = fmaf(xb[3], xb[3], ssq);
    bf16x8 b0 = *(const bf16x8*)(wp + s * 32);
    bf16x8 b1 = *(const bf16x8*)(wp + (size_t)16 * Dn + s * 32);
    acc0 = __builtin_amdgcn_mfma_f32_16x16x32_bf16(af, b0, acc0, 0, 0, 0);
    acc1 = __builtin_amdgcn_mfma_f32_16x16x32_bf16(af, b1, acc1, 0, 0, 0);
  }
  // C/D layout: col = lane&15 (cluster), row = q*4 + r (row within 16)
#pragma unroll
  for (int r = 0; r < 4; ++r) {
    int row = row0 + q * 4 + r;
    logits[(size_t)row * Kn + mr] = acc0[r];
    logits[(size_t)row * Kn + mr + 16] = acc1[r];
  }
  // sumsq keyed by row = lane&15; reduce over the 4 q-groups
  ssq += __shfl_xor(ssq, 16);
  ssq += __shfl_xor(ssq, 32);
  if (lane < 16) invn[row0 + lane] = 1.f / fmaxf(sqrtf(ssq), EPSF);
}

// ---------------- K2: softmax (fp32) -> sa'(=sa*invn) bf16 transposed + colsum -
// One block per b, 512 threads = one row each.
__global__ __launch_bounds__(512) void k2_softmax(const float* __restrict__ logits,
                                                  const float* __restrict__ invn,
                                                  __bf16* __restrict__ sapT,
                                                  float* __restrict__ colsum) {
  __shared__ float csw[8][Kn + 1];
  int b = blockIdx.x, t = threadIdx.x;
  int row = b * Mn + t;
  float inv = invn[row];
  const float* lp = logits + (size_t)row * Kn;
  float v[Kn];
#pragma unroll
  for (int k = 0; k < Kn; ++k) v[k] = lp[k] * inv;
  float mx = v[0];
#pragma unroll
  for (int k = 1; k < Kn; ++k) mx = fmaxf(mx, v[k]);
  float sum = 0.f;
#pragma unroll
  for (int k = 0; k < Kn; ++k) { v[k] = __expf(v[k] - mx); sum += v[k]; }
  float rs = 1.f / sum;
  __bf16* sp = sapT + (size_t)b * (Kn * Mn) + t;
#pragma unroll
  for (int k = 0; k < Kn; ++k) {
    v[k] *= rs;                                   // sa (kept fp32 for colsum)
    sp[(size_t)k * Mn] = (__bf16)(v[k] * inv);    // sa' = sa * invnorm
  }
  // block-wide column sums: wave butterfly, then cross-wave via LDS
#pragma unroll
  for (int k = 0; k < Kn; ++k) {
#pragma unroll
    for (int off = 1; off <= 32; off <<= 1) v[k] += __shfl_xor(v[k], off);
  }
  int wv = t >> 6, lane = t & 63;
#pragma unroll
  for (int k = 0; k < Kn; ++k)
    if (lane == k) csw[wv][k] = v[k];   // static reg index; one lane writes
  __syncthreads();
  if (t < Kn) {
    float s = 0.f;
#pragma unroll
    for (int w = 0; w < 8; ++w) s += csw[w][t];
    colsum[b * Kn + t] = s;
  }
}

// ---------------- K3: agg = sa'^T @ xn via MFMA; vlad = agg - colsum*centroid --
// grid = (b, d-chunk of 256). saT staged in LDS (stride 520, b128-aligned),
// x tile transposed to bf16 LDS (stride 36, b64 reads conflict-free).
#define XS 36
#define AS 520
__global__ __launch_bounds__(256) void k3_agg(const float* __restrict__ x,
                                              const __bf16* __restrict__ sapT,
                                              const float* __restrict__ colsum,
                                              const float* __restrict__ cent,
                                              float* __restrict__ vlad,
                                              float* __restrict__ ssq) {
  __shared__ __bf16 xT[256 * XS];     // [d-col 0..255][m 0..31 (+4 pad)]
  __shared__ __bf16 saT[Kn * AS];     // [k_c 0..31][m 0..511 (+8 pad)]
  __shared__ float csl[Kn];
  int b = blockIdx.x >> 3;
  int dchunk = (blockIdx.x & 7) * 256;
  int t = threadIdx.x;
  // stage sa'^T (32x512 bf16 = 32KB) + colsum
  {
    const __bf16* sg = sapT + (size_t)b * (Kn * Mn);
#pragma unroll
    for (int i = 0; i < 8; ++i) {
      int f = t + 256 * i;           // 0..2047 groups of 8 shorts
      int k = f >> 6;
      int mg = (f & 63) * 8;
      *(bf16x8*)&saT[k * AS + mg] = *(const bf16x8*)(sg + k * Mn + mg);
    }
    if (t < Kn) csl[t] = colsum[b * Kn + t];
  }
  int w = t >> 6, lane = t & 63;
  int mr = lane & 15, q = lane >> 4;      // q in 0..3
  int r_ = t >> 3, qq = t & 7;            // staging map: 32 rows x 8 qq
  const float* xg = x + (size_t)b * Mn * Dn + dchunk;
  f32x4 acc[2][4] = {};
  for (int m0 = 0; m0 < Mn; m0 += 32) {
    __syncthreads();   // protect xT from previous iteration's readers
#pragma unroll
    for (int i = 0; i < 8; ++i) {
      int c0 = (qq + 8 * i) * 4;
      f32x4 xv = *(const f32x4*)(xg + (size_t)(m0 + r_) * Dn + c0);
      xT[(c0 + 0) * XS + r_] = (__bf16)xv[0];
      xT[(c0 + 1) * XS + r_] = (__bf16)xv[1];
      xT[(c0 + 2) * XS + r_] = (__bf16)xv[2];
      xT[(c0 + 3) * XS + r_] = (__bf16)xv[3];
    }
    __syncthreads();
    bf16x8 a0 = *(const bf16x8*)&saT[mr * AS + m0 + q * 8];
    bf16x8 a1 = *(const bf16x8*)&saT[(mr + 16) * AS + m0 + q * 8];
#pragma unroll
    for (int dt = 0; dt < 4; ++dt) {
      int c = w * 64 + dt * 16 + mr;
      bf16x4 lo = *(const bf16x4*)&xT[c * XS + q * 8];
      bf16x4 hi = *(const bf16x4*)&xT[c * XS + q * 8 + 4];
      bf16x8 bv = __builtin_shufflevector(lo, hi, 0, 1, 2, 3, 4, 5, 6, 7);
      acc[0][dt] = __builtin_amdgcn_mfma_f32_16x16x32_bf16(a0, bv, acc[0][dt], 0, 0, 0);
      acc[1][dt] = __builtin_amdgcn_mfma_f32_16x16x32_bf16(a1, bv, acc[1][dt], 0, 0, 0);
    }
  }
  // epilogue: vlad = agg - colsum*centroid (fp32 exact), store + ssq partials
#pragma unroll
  for (int kt = 0; kt < 2; ++kt) {
#pragma unroll
    for (int r = 0; r < 4; ++r) {
      int kc = kt * 16 + q * 4 + r;
      float csv = csl[kc];
      float sqa = 0.f;
#pragma unroll
      for (int dt = 0; dt < 4; ++dt) {
        int col = dchunk + w * 64 + dt * 16 + mr;
        float vv = acc[kt][dt][r] - csv * cent[(size_t)kc * Dn + col];
        vlad[((size_t)(b * Kn + kc)) * Dn + col] = vv;
        sqa = fmaf(vv, vv, sqa);
      }
      sqa += __shfl_xor(sqa, 1); sqa += __shfl_xor(sqa, 2);
      sqa += __shfl_xor(sqa, 4); sqa += __shfl_xor(sqa, 8);
      if (mr == 0) atomicAdd(&ssq[b * Kn + kc], sqa);
    }
  }
}

// ---------------- K4: intra-normalize per (b,k) + global L2 normalize, in place
__global__ __launch_bounds__(256) void k4_norm(float* __restrict__ out,
                                               const float* __restrict__ ssq) {
  __shared__ float rk[Kn];
  __shared__ float us[Kn];
  int b = blockIdx.x >> 4;
  int t = threadIdx.x;
  if (t < Kn) {
    float ss = ssq[b * Kn + t];
    float r = 1.f / fmaxf(sqrtf(ss), EPSF);
    rk[t] = r;
    us[t] = ss * r * r;   // = ||u_k||^2 after intra-norm
  }
  __syncthreads();
  float S = 0.f;
#pragma unroll
  for (int k = 0; k < Kn; ++k) S += us[k];
  float s = 1.f / fmaxf(sqrtf(S), EPSF);
  int chunk = blockIdx.x & 15;
  size_t base = (size_t)b * (Kn * Dn) + (size_t)chunk * 4096;
  f32x4* p = (f32x4*)(out + base);
#pragma unroll
  for (int i = 0; i < 4; ++i) {
    int idx = t + 256 * i;                        // float4 index, 0..1023
    int k = (chunk * 4096 + idx * 4) >> 11;       // 2048 floats per k
    f32x4 v = p[idx];
    float sc = rk[k] * s;
    v[0] *= sc; v[1] *= sc; v[2] *= sc; v[3] *= sc;
    p[idx] = v;
  }
}

extern "C" void kernel_launch(void* const* d_in, const int* in_sizes, int n_in,
                              void* d_out, int out_size, void* d_ws, size_t ws_size,
                              hipStream_t stream) {
  const float* x = (const float*)d_in[0];
  const float* W = (const float*)d_in[1];
  const float* cent = (const float*)d_in[2];
  float* out = (float*)d_out;
  char* ws = (char*)d_ws;
  // ws layout (~2.3 MiB): Wb | invn | sapT | colsum | ssq
  __bf16* Wb = (__bf16*)ws;                                  // 128 KiB
  float* invn = (float*)(ws + (131072));                     // 128 KiB
  __bf16* sapT = (__bf16*)(ws + (262144));                   // 2 MiB
  float* colsum = (float*)(ws + (262144 + 2097152));         // 8 KiB
  float* ssqb = (float*)(ws + (262144 + 2097152 + 8192));    // 8 KiB
  float* logits = out;  // reuse d_out (16 MiB) for logits (4 MiB); consumed by
                        // k2 before k3 overwrites d_out with vlad.
  hipLaunchKernelGGL(k0_prep, dim3(256), dim3(256), 0, stream, W, Wb, ssqb);
  hipLaunchKernelGGL(k1_logits, dim3(512), dim3(256), 0, stream, x, Wb, logits, invn);
  hipLaunchKernelGGL(k2_softmax, dim3(Bn), dim3(512), 0, stream, logits, invn, sapT, colsum);
  hipLaunchKernelGGL(k3_agg, dim3(512), dim3(256), 0, stream, x, sapT, colsum, cent, out, ssqb);
  hipLaunchKernelGGL(k4_norm, dim3(1024), dim3(256), 0, stream, out, ssqb);
}